// Round 3
// baseline (281.578 us; speedup 1.0000x reference)
//
#include <hip/hip_runtime.h>
#include <hip/hip_fp16.h>

// DGCNN forward, fully fused: one workgroup per graph, TPB=512 (8 waves),
// 2 blocks/CU co-resident. f32 on the entire sort-key chain; h1/h2 archived
// to global f16 (conv features only); h3 read back from LDS f32.
//
// Occupancy rules learned R3-R9 (MI355X):
//  * NO launch_bounds min-waves / waves_per_eu hints -> allocator over-shrinks.
//  * 2 blocks x 8 waves co-schedule at VGPR<=64; keep VGPR under 64.
//  * R11: W1^T staged (stride 132) -> k-quad = one ds_read_b128; mid GEMMs
//    col-pair x 6-row with paired W (stride 68). Bit-identical sums.
//  * R12: degree-sorted row->group assignment (counting sort by quad count);
//    csr pre-memset to QPAD; dinv-scale merged into CSR phase; conv weights
//    staged by idle threads; cW2 stride 81.
//  * R13: agg is LDS-throughput-bound while VMEM/L2 idles. Mirror the scaled
//    xw tables to global (distinct buffer per layer -> no L1 staleness);
//    ODD waves gather from L2 mirror, EVEN waves from LDS -> agg bandwidth
//    ~2x. Same f32 bits both paths. Group-total balancing (pass1 desc +
//    pass2 reverse-rank). rank/ord fused (no atomic, one less barrier).

#define TPB   512
#define GRID  512
#define MG    200
#define EPG   6400
#define EE    (512 * EPG)

// ---- LDS layout (byte offsets). Total 75,488 B -> 2 blocks/CU (151/160 KiB) ----
#define OFF_BUFX 0        // f32[201*36] rows 0..200 (row 200 = zeros); later topv[30][100] + conv W
#define OFF_HCUR 28944    // f32[200*36] h of current layer; Phase A/B: staged W1^T [32][132]
#define OFF_CSR  57744    // u8[7200]    CSR (rows padded to x4 entries, pad -> 200)
#define OFF_ROFF 64944    // i32[201] row offsets (padded units)
#define OFF_CNT  65760    // i32[200] degree counts   \ scl f32[201] aliases CNT..CUR
#define OFF_CUR  66560    // i32[200] cursors         /
#define OFF_DINV 67360    // f32[200]
#define OFF_H4   68160    // f32[200] sort key
#define OFF_RANK 68960    // i32[200] (unused, kept for layout stability)
#define OFF_ORD  69760    // i32[30]
#define OFF_BIAS 69880    // f32[64]  double-buffered layer bias
#define OFF_RED  70136    // f32[16] (+8 pad)
#define OFF_WREG 70208    // f32[1088] W2/W3 paired stage [16][8][2][4] stride 68
#define OFF_HIST 74560    // i32[32]  quad-count histogram -> offsets
#define OFF_PERM 74688    // i32[200] degree-sorted row permutation (desc)
#define SMEM_BYTES 75488

#define QPAD 0xC8C8C8C8u   // 4x index 200 (zero row) - exact no-op quad

#define MIR_STRIDE 6432    // floats per graph per layer mirror (201*32)

__device__ __forceinline__ float fast_tanh(float x) {
    const float e = __expf(2.0f * x);
    return 1.0f - 2.0f / (e + 1.0f);
}

__global__ __launch_bounds__(TPB)
void dgcnn_kernel(
    const float* __restrict__ x,
    const int*   __restrict__ ei,
    const float* __restrict__ W1, const float* __restrict__ b1,
    const float* __restrict__ W2, const float* __restrict__ b2,
    const float* __restrict__ W3, const float* __restrict__ b3,
    const float* __restrict__ W4, const float* __restrict__ b4,
    const float* __restrict__ cW1, const float* __restrict__ cb1,
    const float* __restrict__ cW2, const float* __restrict__ cb2,
    const float* __restrict__ lW1, const float* __restrict__ lb1,
    const float* __restrict__ lW2, const float* __restrict__ lb2,
    __half* __restrict__ arch,     // [512][200][64] f16 archive of h1|h2
    float* __restrict__ mir,       // [3][512][201][32] f32 xw mirrors (or null)
    float* __restrict__ out)
{
    extern __shared__ unsigned char smem[];
    float* bufX = (float*)(smem + OFF_BUFX);
    float* hcur = (float*)(smem + OFF_HCUR);
    unsigned char* csr = (unsigned char*)(smem + OFF_CSR);
    int*   roff = (int*)(smem + OFF_ROFF);
    int*   cnt  = (int*)(smem + OFF_CNT);
    int*   cur  = (int*)(smem + OFF_CUR);
    float* dinv = (float*)(smem + OFF_DINV);
    float* h4k  = (float*)(smem + OFF_H4);
    int*   ord  = (int*)(smem + OFF_ORD);
    float* bias = (float*)(smem + OFF_BIAS);
    float* red  = (float*)(smem + OFF_RED);
    float* wreg = (float*)(smem + OFF_WREG);
    int*   hist = (int*)(smem + OFF_HIST);
    int*   perm = (int*)(smem + OFF_PERM);

    const int g = blockIdx.x;
    const int t = threadIdx.x;
    const int gbase = g * MG;
    const float* xg   = x + (size_t)gbase * 128;
    const int*   srcp = ei + (size_t)g * EPG;
    const int*   dstp = ei + (size_t)EE + (size_t)g * EPG;

    float* mir1 = mir ? mir + (size_t)g * MIR_STRIDE : nullptr;
    float* mir2 = mir ? mir + (size_t)512 * MIR_STRIDE + (size_t)g * MIR_STRIDE : nullptr;
    float* mir3 = mir ? mir + (size_t)1024 * MIR_STRIDE + (size_t)g * MIR_STRIDE : nullptr;

    // ---------------- Phase A: stage W1^T -> hcur [32][132] (stride 132 == 4 mod 32),
    // csr memset to QPAD, bias, zeros (LDS + mirror row 200), hist=0. ----
    for (int idx = t; idx < 4096; idx += TPB)
        hcur[(idx & 31) * 132 + (idx >> 5)] = W1[idx];
    for (int idx = t; idx < 1800; idx += TPB)
        ((unsigned*)csr)[idx] = QPAD;
    if (t < 32) bias[t] = b1[t];
    if (t < MG) cnt[t] = 0;
    if (t >= 480) hist[t - 480] = 0;
    if (t >= 256 && t < 292) bufX[200 * 36 + (t - 256)] = 0.f;   // zero row 200
    if (mir && t >= 320 && t < 416) {                            // zero mirror row 200
        const int ly = (t - 320) >> 5, ff = t & 31;
        (ly == 0 ? mir1 : ly == 1 ? mir2 : mir3)[200 * 32 + ff] = 0.f;
    }
    __syncthreads();

    const int f32lane = t & 31;   // feature (output col) 0..31
    const int islot   = t >> 5;   // row slot 0..15

    // ---------------- Phase B: edge in-degree count (int4) + L1 GEMM, one phase ----------
    {
        const int4* d4p = (const int4*)dstp;
        for (int e4 = t; e4 < EPG / 4; e4 += TPB) {
            const int4 d4 = d4p[e4];
            atomicAdd(&cnt[d4.x - gbase], 1);
            atomicAdd(&cnt[d4.y - gbase], 1);
            atomicAdd(&cnt[d4.z - gbase], 1);
            atomicAdd(&cnt[d4.w - gbase], 1);
        }
    }
    {
        const int f = f32lane;
        const float* wt = hcur + f * 132;      // column f of W1, k-major
        const float4* xv = (const float4*)xg;
        #pragma unroll
        for (int j0 = 0; j0 < 12; j0 += 6) {
            const int r0 = islot + 16 * j0;
            float a0 = 0.f, a1 = 0.f, a2 = 0.f, a3 = 0.f, a4 = 0.f, a5 = 0.f;
            #pragma unroll 2
            for (int k4 = 0; k4 < 32; ++k4) {
                const float4 w = *(const float4*)(wt + 4 * k4);
                float4 v;
                v = xv[(r0      ) * 32 + k4]; a0 += v.x*w.x + v.y*w.y + v.z*w.z + v.w*w.w;
                v = xv[(r0 + 16 ) * 32 + k4]; a1 += v.x*w.x + v.y*w.y + v.z*w.z + v.w*w.w;
                v = xv[(r0 + 32 ) * 32 + k4]; a2 += v.x*w.x + v.y*w.y + v.z*w.z + v.w*w.w;
                v = xv[(r0 + 48 ) * 32 + k4]; a3 += v.x*w.x + v.y*w.y + v.z*w.z + v.w*w.w;
                v = xv[(r0 + 64 ) * 32 + k4]; a4 += v.x*w.x + v.y*w.y + v.z*w.z + v.w*w.w;
                v = xv[(r0 + 80 ) * 32 + k4]; a5 += v.x*w.x + v.y*w.y + v.z*w.z + v.w*w.w;
            }
            bufX[(r0      ) * 36 + f] = a0;
            bufX[(r0 + 16 ) * 36 + f] = a1;
            bufX[(r0 + 32 ) * 36 + f] = a2;
            bufX[(r0 + 48 ) * 36 + f] = a3;
            bufX[(r0 + 64 ) * 36 + f] = a4;
            bufX[(r0 + 80 ) * 36 + f] = a5;
        }
        if (islot < 8) {   // rows 192..199
            const int r = 192 + islot;
            float a0 = 0.f;
            #pragma unroll 2
            for (int k4 = 0; k4 < 32; ++k4) {
                const float4 w = *(const float4*)(wt + 4 * k4);
                const float4 v = xv[r * 32 + k4];
                a0 += v.x*w.x + v.y*w.y + v.z*w.z + v.w*w.w;
            }
            bufX[r * 36 + f] = a0;
        }
    }
    __syncthreads();

    // ---------------- Phase C: dinv + hist build + prefix scan over PADDED row lengths ----
    if (t >= 256 && t < 256 + MG) {
        const int i = t - 256;
        const int c = cnt[i];
        dinv[i] = 1.0f / sqrtf((float)(c + 1));
        int qc = (c + 4) >> 2;                 // padded quad count
        if (qc > 31) qc = 31;
        atomicAdd(&hist[31 - qc], 1);          // descending order
    }
    if (t < 64) {
        if (t == 0) roff[0] = 0;
        int carry = 0;
        #pragma unroll
        for (int c = 0; c < 4; ++c) {
            const int i = c * 64 + t;
            int v = (i < MG) ? ((cnt[i] + 4) & ~3) : 0;   // self-loop +1, pad to x4
            #pragma unroll
            for (int off = 1; off < 64; off <<= 1) {
                int u = __shfl_up(v, off);
                if (t >= (int)off) v += u;
            }
            if (i < MG) roff[i + 1] = carry + v;
            carry += __shfl(v, 63);
        }
    }
    __syncthreads();

    // ---------------- Phase D: self-loop entry + cursors + hist exclusive prefix ----------
    if (t < MG) {
        int p = roff[t];
        csr[p] = (unsigned char)t;
        cur[t] = p + 1;
    }
    if (t < 32) {
        const int own = hist[t];
        int v = own;
        #pragma unroll
        for (int off = 1; off < 32; off <<= 1) {
            int u = __shfl_up(v, off);
            if (t >= off) v += u;
        }
        hist[t] = v - own;   // exclusive offsets
    }
    __syncthreads();

    // ---------------- Phase E: CSR placement + dinv-scale bufX (+mir1) + perm scatter -----
    {
        const int4* s4p = (const int4*)srcp;
        const int4* d4p = (const int4*)dstp;
        for (int e4 = t; e4 < EPG / 4; e4 += TPB) {
            const int4 s4 = s4p[e4];
            const int4 d4 = d4p[e4];
            int p;
            p = atomicAdd(&cur[d4.x - gbase], 1); csr[p] = (unsigned char)(s4.x - gbase);
            p = atomicAdd(&cur[d4.y - gbase], 1); csr[p] = (unsigned char)(s4.y - gbase);
            p = atomicAdd(&cur[d4.z - gbase], 1); csr[p] = (unsigned char)(s4.z - gbase);
            p = atomicAdd(&cur[d4.w - gbase], 1); csr[p] = (unsigned char)(s4.w - gbase);
        }
    }
    for (int r = islot; r < MG; r += 16) {
        const float v = bufX[r * 36 + f32lane] * dinv[r];
        bufX[r * 36 + f32lane] = v;
        if (mir) mir1[r * 32 + f32lane] = v;
    }
    if (t < MG) {
        int qc = (cnt[t] + 4) >> 2;
        if (qc > 31) qc = 31;
        const int pos = atomicAdd(&hist[31 - qc], 1);
        perm[pos] = t;   // perm: rows sorted by quad count, descending
    }
    __syncthreads();

    // agg: hcur[d][f] = tanh(dinv[d]*sum_{p} bufX[csr[p]][f] + bias[bb+f]);
    // EVEN waves gather from LDS bufX, ODD waves from the L2-resident mirror
    // (same f32 bits). Group-total balancing: pass1 pairs desc, pass2 reverse.
    auto agg_layer = [&](int archOff, int bb, const float* __restrict__ mirL) {
        const int f4  = (t & 7) << 2;
        const int dsl = t >> 3;   // 0..63
        const bool gp = (mirL != nullptr) && ((t >> 6) & 1);

        auto finish = [&](int d, float a0, float a1, float a2, float a3) {
            const float dv = dinv[d];
            const float o0 = fast_tanh(dv * a0 + bias[bb + f4 + 0]);
            const float o1 = fast_tanh(dv * a1 + bias[bb + f4 + 1]);
            const float o2 = fast_tanh(dv * a2 + bias[bb + f4 + 2]);
            const float o3 = fast_tanh(dv * a3 + bias[bb + f4 + 3]);
            *(float4*)(hcur + d * 36 + f4) = make_float4(o0, o1, o2, o3);
            if (archOff >= 0) {
                const __half2 p01 = __floats2half2_rn(o0, o1);
                const __half2 p23 = __floats2half2_rn(o2, o3);
                __half2* dst = (__half2*)(arch + (size_t)(gbase + d) * 64 + archOff + f4);
                dst[0] = p01;
                dst[1] = p23;
            }
        };

        auto pair_rows = [&](int da, int db) {
            const int p1a = roff[da + 1], p1b = roff[db + 1];
            int pa = roff[da], pb = roff[db];
            const int na = (p1a - pa) >> 2, nb = (p1b - pb) >> 2;
            const int iters = na > nb ? na : nb;
            unsigned qa = *(const unsigned*)(csr + pa);
            unsigned qb = *(const unsigned*)(csr + pb);
            float a0=0.f,a1=0.f,a2=0.f,a3=0.f, c0=0.f,c1=0.f,c2=0.f,c3=0.f;
            for (int i = 0; i < iters; ++i) {
                pa += 4; pb += 4;
                const unsigned qa_n = (pa < p1a) ? *(const unsigned*)(csr + pa) : QPAD;
                const unsigned qb_n = (pb < p1b) ? *(const unsigned*)(csr + pb) : QPAD;
                float4 v;
                v = *(const float4*)(bufX + (qa & 255u) * 36 + f4);         a0+=v.x; a1+=v.y; a2+=v.z; a3+=v.w;
                v = *(const float4*)(bufX + ((qa >> 8) & 255u) * 36 + f4);  a0+=v.x; a1+=v.y; a2+=v.z; a3+=v.w;
                v = *(const float4*)(bufX + ((qa >> 16) & 255u) * 36 + f4); a0+=v.x; a1+=v.y; a2+=v.z; a3+=v.w;
                v = *(const float4*)(bufX + (qa >> 24) * 36 + f4);          a0+=v.x; a1+=v.y; a2+=v.z; a3+=v.w;
                v = *(const float4*)(bufX + (qb & 255u) * 36 + f4);         c0+=v.x; c1+=v.y; c2+=v.z; c3+=v.w;
                v = *(const float4*)(bufX + ((qb >> 8) & 255u) * 36 + f4);  c0+=v.x; c1+=v.y; c2+=v.z; c3+=v.w;
                v = *(const float4*)(bufX + ((qb >> 16) & 255u) * 36 + f4); c0+=v.x; c1+=v.y; c2+=v.z; c3+=v.w;
                v = *(const float4*)(bufX + (qb >> 24) * 36 + f4);          c0+=v.x; c1+=v.y; c2+=v.z; c3+=v.w;
                qa = qa_n; qb = qb_n;
            }
            finish(da, a0, a1, a2, a3);
            finish(db, c0, c1, c2, c3);
        };

        auto one_row = [&](int d) {
            const int p1 = roff[d + 1];
            int p = roff[d];
            const int iters = (p1 - p) >> 2;
            unsigned q = *(const unsigned*)(csr + p);
            float a0=0.f,a1=0.f,a2=0.f,a3=0.f;
            for (int i = 0; i < iters; ++i) {
                p += 4;
                const unsigned q_n = (p < p1) ? *(const unsigned*)(csr + p) : QPAD;
                float4 v;
                v = *(const float4*)(bufX + (q & 255u) * 36 + f4);         a0+=v.x; a1+=v.y; a2+=v.z; a3+=v.w;
                v = *(const float4*)(bufX + ((q >> 8) & 255u) * 36 + f4);  a0+=v.x; a1+=v.y; a2+=v.z; a3+=v.w;
                v = *(const float4*)(bufX + ((q >> 16) & 255u) * 36 + f4); a0+=v.x; a1+=v.y; a2+=v.z; a3+=v.w;
                v = *(const float4*)(bufX + (q >> 24) * 36 + f4);          a0+=v.x; a1+=v.y; a2+=v.z; a3+=v.w;
                q = q_n;
            }
            finish(d, a0, a1, a2, a3);
        };

        auto pair_rows_G = [&](int da, int db) {
            const int p1a = roff[da + 1], p1b = roff[db + 1];
            int pa = roff[da], pb = roff[db];
            const int na = (p1a - pa) >> 2, nb = (p1b - pb) >> 2;
            const int iters = na > nb ? na : nb;
            unsigned qa = *(const unsigned*)(csr + pa);
            unsigned qb = *(const unsigned*)(csr + pb);
            float a0=0.f,a1=0.f,a2=0.f,a3=0.f, c0=0.f,c1=0.f,c2=0.f,c3=0.f;
            for (int i = 0; i < iters; ++i) {
                pa += 4; pb += 4;
                const unsigned qa_n = (pa < p1a) ? *(const unsigned*)(csr + pa) : QPAD;
                const unsigned qb_n = (pb < p1b) ? *(const unsigned*)(csr + pb) : QPAD;
                float4 v;
                v = *(const float4*)(mirL + (qa & 255u) * 32 + f4);         a0+=v.x; a1+=v.y; a2+=v.z; a3+=v.w;
                v = *(const float4*)(mirL + ((qa >> 8) & 255u) * 32 + f4);  a0+=v.x; a1+=v.y; a2+=v.z; a3+=v.w;
                v = *(const float4*)(mirL + ((qa >> 16) & 255u) * 32 + f4); a0+=v.x; a1+=v.y; a2+=v.z; a3+=v.w;
                v = *(const float4*)(mirL + (qa >> 24) * 32 + f4);          a0+=v.x; a1+=v.y; a2+=v.z; a3+=v.w;
                v = *(const float4*)(mirL + (qb & 255u) * 32 + f4);         c0+=v.x; c1+=v.y; c2+=v.z; c3+=v.w;
                v = *(const float4*)(mirL + ((qb >> 8) & 255u) * 32 + f4);  c0+=v.x; c1+=v.y; c2+=v.z; c3+=v.w;
                v = *(const float4*)(mirL + ((qb >> 16) & 255u) * 32 + f4); c0+=v.x; c1+=v.y; c2+=v.z; c3+=v.w;
                v = *(const float4*)(mirL + (qb >> 24) * 32 + f4);          c0+=v.x; c1+=v.y; c2+=v.z; c3+=v.w;
                qa = qa_n; qb = qb_n;
            }
            finish(da, a0, a1, a2, a3);
            finish(db, c0, c1, c2, c3);
        };

        auto one_row_G = [&](int d) {
            const int p1 = roff[d + 1];
            int p = roff[d];
            const int iters = (p1 - p) >> 2;
            unsigned q = *(const unsigned*)(csr + p);
            float a0=0.f,a1=0.f,a2=0.f,a3=0.f;
            for (int i = 0; i < iters; ++i) {
                p += 4;
                const unsigned q_n = (p < p1) ? *(const unsigned*)(csr + p) : QPAD;
                float4 v;
                v = *(const float4*)(mirL + (q & 255u) * 32 + f4);         a0+=v.x; a1+=v.y; a2+=v.z; a3+=v.w;
                v = *(const float4*)(mirL + ((q >> 8) & 255u) * 32 + f4);  a0+=v.x; a1+=v.y; a2+=v.z; a3+=v.w;
                v = *(const float4*)(mirL + ((q >> 16) & 255u) * 32 + f4); a0+=v.x; a1+=v.y; a2+=v.z; a3+=v.w;
                v = *(const float4*)(mirL + (q >> 24) * 32 + f4);          a0+=v.x; a1+=v.y; a2+=v.z; a3+=v.w;
                q = q_n;
            }
            finish(d, a0, a1, a2, a3);
        };

        // Pass 1: groups g take sorted pairs (perm[2g], perm[2g+1]) [ranks 0..127].
        // Pass 2 balanced: group-total = pass1+pass2 (no sync between) -> heaviest
        // pass1 groups get lightest pass2 items. Wave 0 (dsl<8) takes the 8 tiny
        // pairs; groups 8..63 take singles perm[191-dsl]. No intra-wave divergence.
        if (gp) {
            pair_rows_G(perm[2 * dsl], perm[2 * dsl + 1]);
            if (dsl < 8) pair_rows_G(perm[184 + 7 - dsl], perm[192 + 7 - dsl]);
            else         one_row_G(perm[191 - dsl]);
        } else {
            pair_rows(perm[2 * dsl], perm[2 * dsl + 1]);
            if (dsl < 8) pair_rows(perm[184 + 7 - dsl], perm[192 + 7 - dsl]);
            else         one_row(perm[191 - dsl]);
        }
    };

    auto gemm_mid = [&](const float* __restrict__ src, float* __restrict__ mirW) {
        // bufX = (src[200x32] @ W[32x32]) scaled by dinv[row]; W staged paired in
        // wreg: [f2][k4][c][4] stride 68. Col-pair x 6-row mapping. Results also
        // mirrored to global for the odd-wave agg path.
        const int f2 = t & 15;    // column pair: cols 2*f2, 2*f2+1
        const int sl = t >> 4;    // row slot 0..31
        const float* wp = wreg + f2 * 68;
        {
            float a0A=0.f,a1A=0.f,a2A=0.f,a3A=0.f,a4A=0.f,a5A=0.f;
            float a0B=0.f,a1B=0.f,a2B=0.f,a3B=0.f,a4B=0.f,a5B=0.f;
            #pragma unroll 2
            for (int k4 = 0; k4 < 8; ++k4) {
                const float4 wA = *(const float4*)(wp + k4 * 8);
                const float4 wB = *(const float4*)(wp + k4 * 8 + 4);
                float4 v;
                v = *(const float4*)(src + (sl       ) * 36 + 4 * k4);
                a0A += v.x*wA.x + v.y*wA.y + v.z*wA.z + v.w*wA.w;
                a0B += v.x*wB.x + v.y*wB.y + v.z*wB.z + v.w*wB.w;
                v = *(const float4*)(src + (sl + 32  ) * 36 + 4 * k4);
                a1A += v.x*wA.x + v.y*wA.y + v.z*wA.z + v.w*wA.w;
                a1B += v.x*wB.x + v.y*wB.y + v.z*wB.z + v.w*wB.w;
                v = *(const float4*)(src + (sl + 64  ) * 36 + 4 * k4);
                a2A += v.x*wA.x + v.y*wA.y + v.z*wA.z + v.w*wA.w;
                a2B += v.x*wB.x + v.y*wB.y + v.z*wB.z + v.w*wB.w;
                v = *(const float4*)(src + (sl + 96  ) * 36 + 4 * k4);
                a3A += v.x*wA.x + v.y*wA.y + v.z*wA.z + v.w*wA.w;
                a3B += v.x*wB.x + v.y*wB.y + v.z*wB.z + v.w*wB.w;
                v = *(const float4*)(src + (sl + 128 ) * 36 + 4 * k4);
                a4A += v.x*wA.x + v.y*wA.y + v.z*wA.z + v.w*wA.w;
                a4B += v.x*wB.x + v.y*wB.y + v.z*wB.z + v.w*wB.w;
                v = *(const float4*)(src + (sl + 160 ) * 36 + 4 * k4);
                a5A += v.x*wA.x + v.y*wA.y + v.z*wA.z + v.w*wA.w;
                a5B += v.x*wB.x + v.y*wB.y + v.z*wB.z + v.w*wB.w;
            }
            const int c0 = 2 * f2;
            float2 r0v = make_float2(dinv[sl      ] * a0A, dinv[sl      ] * a0B);
            float2 r1v = make_float2(dinv[sl + 32 ] * a1A, dinv[sl + 32 ] * a1B);
            float2 r2v = make_float2(dinv[sl + 64 ] * a2A, dinv[sl + 64 ] * a2B);
            float2 r3v = make_float2(dinv[sl + 96 ] * a3A, dinv[sl + 96 ] * a3B);
            float2 r4v = make_float2(dinv[sl + 128] * a4A, dinv[sl + 128] * a4B);
            float2 r5v = make_float2(dinv[sl + 160] * a5A, dinv[sl + 160] * a5B);
            *(float2*)(bufX + (sl       ) * 36 + c0) = r0v;
            *(float2*)(bufX + (sl + 32  ) * 36 + c0) = r1v;
            *(float2*)(bufX + (sl + 64  ) * 36 + c0) = r2v;
            *(float2*)(bufX + (sl + 96  ) * 36 + c0) = r3v;
            *(float2*)(bufX + (sl + 128 ) * 36 + c0) = r4v;
            *(float2*)(bufX + (sl + 160 ) * 36 + c0) = r5v;
            if (mirW) {
                *(float2*)(mirW + (sl       ) * 32 + c0) = r0v;
                *(float2*)(mirW + (sl + 32  ) * 32 + c0) = r1v;
                *(float2*)(mirW + (sl + 64  ) * 32 + c0) = r2v;
                *(float2*)(mirW + (sl + 96  ) * 32 + c0) = r3v;
                *(float2*)(mirW + (sl + 128 ) * 32 + c0) = r4v;
                *(float2*)(mirW + (sl + 160 ) * 32 + c0) = r5v;
            }
        }
        if (sl < 8) {   // rows 192..199
            const int r = 192 + sl;
            float aA = 0.f, aB = 0.f;
            #pragma unroll 2
            for (int k4 = 0; k4 < 8; ++k4) {
                const float4 wA = *(const float4*)(wp + k4 * 8);
                const float4 wB = *(const float4*)(wp + k4 * 8 + 4);
                const float4 v = *(const float4*)(src + r * 36 + 4 * k4);
                aA += v.x*wA.x + v.y*wA.y + v.z*wA.z + v.w*wA.w;
                aB += v.x*wB.x + v.y*wB.y + v.z*wB.z + v.w*wB.w;
            }
            float2 rv = make_float2(dinv[r] * aA, dinv[r] * aB);
            *(float2*)(bufX + r * 36 + 2 * f2) = rv;
            if (mirW) *(float2*)(mirW + r * 32 + 2 * f2) = rv;
        }
    };

    // paired-W staging: wreg[f2*68 + k4*8 + c*4 + j] = W[(4k4+j)*32 + 2f2+c]
    auto stage_w_paired = [&](const float* __restrict__ W) {
        for (int idx = t; idx < 1024; idx += TPB) {
            const int k = idx >> 5, f = idx & 31;
            wreg[(f >> 1) * 68 + (k >> 2) * 8 + ((f & 1) << 2) + (k & 3)] = W[idx];
        }
    };

    // ---------------- Layer 1 agg (+ stage W2/b2 in-phase, bias double-buffer) --------
    agg_layer(0, 0, mir1);    // h1 -> arch[:,0:32)
    stage_w_paired(W2);
    if (t < 32) bias[32 + t] = b2[t];
    __syncthreads();

    // ---------------- Layer 2 ----------------
    gemm_mid(hcur, mir2);
    __syncthreads();
    agg_layer(32, 32, mir2);  // h2 -> arch[:,32:64)
    stage_w_paired(W3);
    if (t < 32) bias[t] = b3[t];
    __syncthreads();

    // ---------------- Layer 3 ----------------
    gemm_mid(hcur, mir3);
    __syncthreads();
    agg_layer(-1, 0, mir3);   // h3 stays in hcur (f32), not archived
    __syncthreads();

    // conv weight staging targets (bufX dead after agg3 barrier)
    float* topv = bufX;           // [30][100] = 3000 floats
    float* cw   = bufX + 3008;    // cW1: [0,1552)  cW2 stride-81: [1552,5695); ends 7151 <= 7236

    // ---------------- Layer 4 (Fout=1): scl = dinv * (h3 @ W4); scl[200]=0 ----------------
    // Idle threads 256..511 stage cW1; threads 208..255 stage conv biases.
    float* scl = (float*)(smem + OFF_CNT);   // 400 floats available (cnt+cur dead)
    if (t < MG) {
        float a = 0.f;
        #pragma unroll 8
        for (int k = 0; k < 32; ++k) a += hcur[t * 36 + k] * W4[k];
        scl[t] = dinv[t] * a;
    }
    if (t == 200) scl[200] = 0.f;
    if (t >= 256) {
        for (int idx = t - 256; idx < 1552; idx += 256) cw[idx] = cW1[idx];
    } else if (t >= 208 && t < 224) {
        bias[t - 208] = cb1[t - 208];
    } else if (t >= 224 && t < 256) {
        bias[16 + (t - 224)] = cb2[t - 224];
    }
    __syncthreads();
    // h4k gather; idle threads stage cW2 at stride 81 (odd -> no bank aliasing in conv2)
    if (t < MG) {
        const int p0 = roff[t], p1 = roff[t + 1];
        float s = 0.f;
        for (int p = p0; p < p1; p += 4) {
            const unsigned q = *(const unsigned*)(csr + p);
            s += scl[q & 255u] + scl[(q >> 8) & 255u]
               + scl[(q >> 16) & 255u] + scl[q >> 24];
        }
        h4k[t] = fast_tanh(dinv[t] * s + b4[0]);
    }
    if (t >= 256) {
        for (int idx = t - 256; idx < 2560; idx += 256) {
            const int o = idx / 80, r = idx - o * 80;
            cw[1552 + o * 81 + r] = cW2[idx];
        }
    }
    __syncthreads();

    // ---------------- SortPool: fused exact stable rank + ord scatter ----------------
    // (desc value, asc index). Each of 200 threads ranks itself over all 200;
    // rank is final locally -> scatter ord immediately, no atomic, one phase.
    if (t < MG) {
        const float vi = h4k[t];
        int r = 0;
        for (int j = 0; j < MG; ++j) {
            const float vj = h4k[j];
            r += (vj > vi || (vj == vi && j < t)) ? 1 : 0;
        }
        if (r < 30) ord[r] = t;
    }
    __syncthreads();

    // ---------------- Gather top-30 features ----------
    for (int idx = t; idx < 2910; idx += TPB) {   // 30*97 grid-stride
        const int kk = idx / 97;
        const int ff = idx - kk * 97;
        const int nd = ord[kk];
        float v;
        if      (ff < 64) v = __half2float(arch[(size_t)(gbase + nd) * 64 + ff]);
        else if (ff < 96) v = hcur[nd * 36 + (ff - 64)];   // h3, f32
        else              v = h4k[nd];
        topv[kk * 100 + ff] = v;
    }
    __syncthreads();

    // conv scratch in hcur (dead after gather barrier)
    float* c1p2 = hcur;           // [16][30]
    float* c1pl = hcur + 480;     // [16][16]
    float* flat = hcur + 736;     // [352]
    float* hlin = hcur + 1088;    // [128]

    // ---------------- Conv1 (97->16 per slot) + ReLU ----------------
    if (t < 480) {
        const int o  = t & 15;
        const int tt = t >> 4;
        float a = bias[o];
        const float* wrow = cw + o * 97;
        const float* trow = topv + tt * 100;
        #pragma unroll 4
        for (int f = 0; f < 97; ++f) a += wrow[f] * trow[f];
        c1p2[o * 30 + tt] = fmaxf(a, 0.f);
    }
    __syncthreads();

    // ---------------- MaxPool1d(2,2): 30 -> 15 ----------------
    if (t < 240) {
        const int o  = t & 15;
        const int tp = t >> 4;
        c1pl[o * 16 + tp] = fmaxf(c1p2[o * 30 + 2 * tp], c1p2[o * 30 + 2 * tp + 1]);
    }
    __syncthreads();

    // ---------------- Conv2 (16->32, k=5) + ReLU -> flat; init hlin ----------------
    if (t < 352) {
        const int o  = t & 31;
        const int tt = t >> 5;
        float a = bias[16 + o];
        const float* w2r = cw + 1552 + o * 81;
        #pragma unroll
        for (int i2 = 0; i2 < 16; ++i2) {
            #pragma unroll
            for (int kk = 0; kk < 5; ++kk)
                a += w2r[i2 * 5 + kk] * c1pl[i2 * 16 + tt + kk];
        }
        flat[o * 11 + tt] = fmaxf(a, 0.f);
    } else if (t >= 352 && t < 480) {
        hlin[t - 352] = lb1[t - 352];
    }
    __syncthreads();

    // ---------------- Linear 352->128 (split-K over 4 groups of 88) ----------------
    {
        const int f  = t & 127;
        const int kc = t >> 7;   // 0..3
        float a = 0.f;
        const int k0 = kc * 88;
        #pragma unroll 4
        for (int kk = k0; kk < k0 + 88; ++kk) a += flat[kk] * lW1[kk * 128 + f];
        atomicAdd(&hlin[f], a);
    }
    __syncthreads();

    // ---------------- ReLU -> Linear 128->1 -> sigmoid ----------------
    if (t < 128) {
        float p = fmaxf(hlin[t], 0.f) * lW2[t];
        #pragma unroll
        for (int off = 32; off > 0; off >>= 1) p += __shfl_down(p, off);
        if ((t & 63) == 0) red[t >> 6] = p;
    }
    __syncthreads();
    if (t == 0) {
        const float z = red[0] + red[1] + lb2[0];
        out[g] = 1.f / (1.f + expf(-z));
    }
}

extern "C" void kernel_launch(void* const* d_in, const int* in_sizes, int n_in,
                              void* d_out, int out_size, void* d_ws, size_t ws_size,
                              hipStream_t stream) {
    (void)in_sizes; (void)n_in; (void)out_size;
    const float* x   = (const float*)d_in[0];
    const int*   ei  = (const int*)d_in[1];
    const float* W1  = (const float*)d_in[3];  const float* b1  = (const float*)d_in[4];
    const float* W2  = (const float*)d_in[5];  const float* b2  = (const float*)d_in[6];
    const float* W3  = (const float*)d_in[7];  const float* b3  = (const float*)d_in[8];
    const float* W4  = (const float*)d_in[9];  const float* b4  = (const float*)d_in[10];
    const float* cW1 = (const float*)d_in[11]; const float* cb1 = (const float*)d_in[12];
    const float* cW2 = (const float*)d_in[13]; const float* cb2 = (const float*)d_in[14];
    const float* lW1 = (const float*)d_in[15]; const float* lb1 = (const float*)d_in[16];
    const float* lW2 = (const float*)d_in[17]; const float* lb2 = (const float*)d_in[18];
    float* out = (float*)d_out;

    __half* arch = (__half*)d_ws;   // 512*200*64*2 = 13,107,200 B
    const size_t ARCH_BYTES = (size_t)512 * 200 * 64 * 2;
    const size_t MIR_BYTES  = (size_t)3 * 512 * MIR_STRIDE * 4;   // 39,518,208 B
    float* mir = (ws_size >= ARCH_BYTES + MIR_BYTES)
               ? (float*)((char*)d_ws + ARCH_BYTES) : nullptr;

    hipFuncSetAttribute((const void*)dgcnn_kernel,
                        hipFuncAttributeMaxDynamicSharedMemorySize, SMEM_BYTES);

    dgcnn_kernel<<<GRID, TPB, SMEM_BYTES, stream>>>(
        x, ei, W1, b1, W2, b2, W3, b3, W4, b4,
        cW1, cb1, cW2, cb2, lW1, lb1, lW2, lb2, arch, mir, out);
}

// Round 4
// 235.456 us; speedup vs baseline: 1.1959x; 1.1959x over previous
//
#include <hip/hip_runtime.h>
#include <hip/hip_fp16.h>

// DGCNN forward, fully fused: one workgroup per graph, TPB=512 (8 waves),
// 2 blocks/CU co-resident. f32 on the entire sort-key chain; h1/h2 archived
// to global f16 (conv features only); h3 read back from LDS f32.
//
// Occupancy rules learned R3-R9 (MI355X):
//  * NO launch_bounds min-waves / waves_per_eu hints -> allocator over-shrinks.
//  * 2 blocks x 8 waves co-schedule at VGPR<=64; keep VGPR under 64.
//  * R11: W1^T staged (stride 132) -> k-quad = one ds_read_b128; mid GEMMs
//    col-pair x 6-row with paired W (stride 68). Bit-identical sums.
//  * R12: degree-sorted row->group assignment (counting sort by quad count);
//    csr pre-memset to QPAD; dinv-scale merged into CSR phase; conv weights
//    staged by idle threads; cW2 stride 81.
//  * R13 FAILED: global-mirror dual-path agg -> 8 in-flight 64-bit addresses
//    pushed VGPR 60->68, occupancy 40->22.6% (2 blocks/CU -> 1). Reverted.
//    Do NOT add per-entry 64-bit address streams to the agg loop.
//  * R14: register-neutral wins kept from R13: (a) group-TOTAL balancing --
//    pass1 pairs descending, pass2 reverse-rank (heaviest pass1 group gets
//    lightest pass2 item; wall 20.9 -> ~18 iters); (b) fused rank+ord scatter
//    (no atomic, one less barrier; LDS rank reads are broadcasts).

#define TPB   512
#define GRID  512
#define MG    200
#define EPG   6400
#define EE    (512 * EPG)

// ---- LDS layout (byte offsets). Total 75,488 B -> 2 blocks/CU (151/160 KiB) ----
#define OFF_BUFX 0        // f32[201*36] rows 0..200 (row 200 = zeros); later topv[30][100] + conv W
#define OFF_HCUR 28944    // f32[200*36] h of current layer; Phase A/B: staged W1^T [32][132]
#define OFF_CSR  57744    // u8[7200]    CSR (rows padded to x4 entries, pad -> 200)
#define OFF_ROFF 64944    // i32[201] row offsets (padded units)
#define OFF_CNT  65760    // i32[200] degree counts   \ scl f32[201] aliases CNT..CUR
#define OFF_CUR  66560    // i32[200] cursors         /
#define OFF_DINV 67360    // f32[200]
#define OFF_H4   68160    // f32[200] sort key
#define OFF_ORD  69760    // i32[30]
#define OFF_BIAS 69880    // f32[64]  double-buffered layer bias
#define OFF_RED  70136    // f32[16] (+8 pad)
#define OFF_WREG 70208    // f32[1088] W2/W3 paired stage [16][8][2][4] stride 68
#define OFF_HIST 74560    // i32[32]  quad-count histogram -> offsets
#define OFF_PERM 74688    // i32[200] degree-sorted row permutation (desc)
#define SMEM_BYTES 75488

#define QPAD 0xC8C8C8C8u   // 4x index 200 (zero row) - exact no-op quad

__device__ __forceinline__ float fast_tanh(float x) {
    const float e = __expf(2.0f * x);
    return 1.0f - 2.0f / (e + 1.0f);
}

__global__ __launch_bounds__(TPB)
void dgcnn_kernel(
    const float* __restrict__ x,
    const int*   __restrict__ ei,
    const float* __restrict__ W1, const float* __restrict__ b1,
    const float* __restrict__ W2, const float* __restrict__ b2,
    const float* __restrict__ W3, const float* __restrict__ b3,
    const float* __restrict__ W4, const float* __restrict__ b4,
    const float* __restrict__ cW1, const float* __restrict__ cb1,
    const float* __restrict__ cW2, const float* __restrict__ cb2,
    const float* __restrict__ lW1, const float* __restrict__ lb1,
    const float* __restrict__ lW2, const float* __restrict__ lb2,
    __half* __restrict__ arch,     // [512][200][64] f16 archive of h1|h2
    float* __restrict__ out)
{
    extern __shared__ unsigned char smem[];
    float* bufX = (float*)(smem + OFF_BUFX);
    float* hcur = (float*)(smem + OFF_HCUR);
    unsigned char* csr = (unsigned char*)(smem + OFF_CSR);
    int*   roff = (int*)(smem + OFF_ROFF);
    int*   cnt  = (int*)(smem + OFF_CNT);
    int*   cur  = (int*)(smem + OFF_CUR);
    float* dinv = (float*)(smem + OFF_DINV);
    float* h4k  = (float*)(smem + OFF_H4);
    int*   ord  = (int*)(smem + OFF_ORD);
    float* bias = (float*)(smem + OFF_BIAS);
    float* red  = (float*)(smem + OFF_RED);
    float* wreg = (float*)(smem + OFF_WREG);
    int*   hist = (int*)(smem + OFF_HIST);
    int*   perm = (int*)(smem + OFF_PERM);

    const int g = blockIdx.x;
    const int t = threadIdx.x;
    const int gbase = g * MG;
    const float* xg   = x + (size_t)gbase * 128;
    const int*   srcp = ei + (size_t)g * EPG;
    const int*   dstp = ei + (size_t)EE + (size_t)g * EPG;

    // ---------------- Phase A: stage W1^T -> hcur [32][132] (stride 132 == 4 mod 32),
    // csr memset to QPAD (kills pad-fill phase), bias, zeros, hist=0. ----
    for (int idx = t; idx < 4096; idx += TPB)
        hcur[(idx & 31) * 132 + (idx >> 5)] = W1[idx];
    for (int idx = t; idx < 1800; idx += TPB)
        ((unsigned*)csr)[idx] = QPAD;
    if (t < 32) bias[t] = b1[t];
    if (t < MG) cnt[t] = 0;
    if (t >= 480) hist[t - 480] = 0;
    if (t >= 256 && t < 292) bufX[200 * 36 + (t - 256)] = 0.f;   // zero row 200
    __syncthreads();

    const int f32lane = t & 31;   // feature (output col) 0..31
    const int islot   = t >> 5;   // row slot 0..15

    // ---------------- Phase B: edge in-degree count (int4) + L1 GEMM, one phase ----------
    {
        const int4* d4p = (const int4*)dstp;
        for (int e4 = t; e4 < EPG / 4; e4 += TPB) {
            const int4 d4 = d4p[e4];
            atomicAdd(&cnt[d4.x - gbase], 1);
            atomicAdd(&cnt[d4.y - gbase], 1);
            atomicAdd(&cnt[d4.z - gbase], 1);
            atomicAdd(&cnt[d4.w - gbase], 1);
        }
    }
    {
        const int f = f32lane;
        const float* wt = hcur + f * 132;      // column f of W1, k-major
        const float4* xv = (const float4*)xg;
        #pragma unroll
        for (int j0 = 0; j0 < 12; j0 += 6) {
            const int r0 = islot + 16 * j0;
            float a0 = 0.f, a1 = 0.f, a2 = 0.f, a3 = 0.f, a4 = 0.f, a5 = 0.f;
            #pragma unroll 2
            for (int k4 = 0; k4 < 32; ++k4) {
                const float4 w = *(const float4*)(wt + 4 * k4);
                float4 v;
                v = xv[(r0      ) * 32 + k4]; a0 += v.x*w.x + v.y*w.y + v.z*w.z + v.w*w.w;
                v = xv[(r0 + 16 ) * 32 + k4]; a1 += v.x*w.x + v.y*w.y + v.z*w.z + v.w*w.w;
                v = xv[(r0 + 32 ) * 32 + k4]; a2 += v.x*w.x + v.y*w.y + v.z*w.z + v.w*w.w;
                v = xv[(r0 + 48 ) * 32 + k4]; a3 += v.x*w.x + v.y*w.y + v.z*w.z + v.w*w.w;
                v = xv[(r0 + 64 ) * 32 + k4]; a4 += v.x*w.x + v.y*w.y + v.z*w.z + v.w*w.w;
                v = xv[(r0 + 80 ) * 32 + k4]; a5 += v.x*w.x + v.y*w.y + v.z*w.z + v.w*w.w;
            }
            bufX[(r0      ) * 36 + f] = a0;
            bufX[(r0 + 16 ) * 36 + f] = a1;
            bufX[(r0 + 32 ) * 36 + f] = a2;
            bufX[(r0 + 48 ) * 36 + f] = a3;
            bufX[(r0 + 64 ) * 36 + f] = a4;
            bufX[(r0 + 80 ) * 36 + f] = a5;
        }
        if (islot < 8) {   // rows 192..199
            const int r = 192 + islot;
            float a0 = 0.f;
            #pragma unroll 2
            for (int k4 = 0; k4 < 32; ++k4) {
                const float4 w = *(const float4*)(wt + 4 * k4);
                const float4 v = xv[r * 32 + k4];
                a0 += v.x*w.x + v.y*w.y + v.z*w.z + v.w*w.w;
            }
            bufX[r * 36 + f] = a0;
        }
    }
    __syncthreads();

    // ---------------- Phase C: dinv + hist build + prefix scan over PADDED row lengths ----
    if (t >= 256 && t < 256 + MG) {
        const int i = t - 256;
        const int c = cnt[i];
        dinv[i] = 1.0f / sqrtf((float)(c + 1));
        int qc = (c + 4) >> 2;                 // padded quad count
        if (qc > 31) qc = 31;
        atomicAdd(&hist[31 - qc], 1);          // descending order
    }
    if (t < 64) {
        if (t == 0) roff[0] = 0;
        int carry = 0;
        #pragma unroll
        for (int c = 0; c < 4; ++c) {
            const int i = c * 64 + t;
            int v = (i < MG) ? ((cnt[i] + 4) & ~3) : 0;   // self-loop +1, pad to x4
            #pragma unroll
            for (int off = 1; off < 64; off <<= 1) {
                int u = __shfl_up(v, off);
                if (t >= (int)off) v += u;
            }
            if (i < MG) roff[i + 1] = carry + v;
            carry += __shfl(v, 63);
        }
    }
    __syncthreads();

    // ---------------- Phase D: self-loop entry + cursors + hist exclusive prefix ----------
    if (t < MG) {
        int p = roff[t];
        csr[p] = (unsigned char)t;
        cur[t] = p + 1;
    }
    if (t < 32) {
        const int own = hist[t];
        int v = own;
        #pragma unroll
        for (int off = 1; off < 32; off <<= 1) {
            int u = __shfl_up(v, off);
            if (t >= off) v += u;
        }
        hist[t] = v - own;   // exclusive offsets
    }
    __syncthreads();

    // ---------------- Phase E: CSR placement + dinv-scale bufX + perm scatter ------------
    {
        const int4* s4p = (const int4*)srcp;
        const int4* d4p = (const int4*)dstp;
        for (int e4 = t; e4 < EPG / 4; e4 += TPB) {
            const int4 s4 = s4p[e4];
            const int4 d4 = d4p[e4];
            int p;
            p = atomicAdd(&cur[d4.x - gbase], 1); csr[p] = (unsigned char)(s4.x - gbase);
            p = atomicAdd(&cur[d4.y - gbase], 1); csr[p] = (unsigned char)(s4.y - gbase);
            p = atomicAdd(&cur[d4.z - gbase], 1); csr[p] = (unsigned char)(s4.z - gbase);
            p = atomicAdd(&cur[d4.w - gbase], 1); csr[p] = (unsigned char)(s4.w - gbase);
        }
    }
    for (int r = islot; r < MG; r += 16) {
        bufX[r * 36 + f32lane] *= dinv[r];
    }
    if (t < MG) {
        int qc = (cnt[t] + 4) >> 2;
        if (qc > 31) qc = 31;
        const int pos = atomicAdd(&hist[31 - qc], 1);
        perm[pos] = t;   // perm: rows sorted by quad count, descending
    }
    __syncthreads();

    // agg: hcur[d][f] = tanh(dinv[d]*sum_{p} bufX[csr[p]][f] + bias[bb+f]);
    // 2-row interleaved + csr-quad prefetch; degree-sorted perm assignment with
    // group-TOTAL balancing (pass1 desc + pass2 reverse-rank, no sync between).
    auto agg_layer = [&](int archOff, int bb) {
        const int f4  = (t & 7) << 2;
        const int dsl = t >> 3;   // 0..63

        auto finish = [&](int d, float a0, float a1, float a2, float a3) {
            const float dv = dinv[d];
            const float o0 = fast_tanh(dv * a0 + bias[bb + f4 + 0]);
            const float o1 = fast_tanh(dv * a1 + bias[bb + f4 + 1]);
            const float o2 = fast_tanh(dv * a2 + bias[bb + f4 + 2]);
            const float o3 = fast_tanh(dv * a3 + bias[bb + f4 + 3]);
            *(float4*)(hcur + d * 36 + f4) = make_float4(o0, o1, o2, o3);
            if (archOff >= 0) {
                const __half2 p01 = __floats2half2_rn(o0, o1);
                const __half2 p23 = __floats2half2_rn(o2, o3);
                __half2* dst = (__half2*)(arch + (size_t)(gbase + d) * 64 + archOff + f4);
                dst[0] = p01;
                dst[1] = p23;
            }
        };

        auto pair_rows = [&](int da, int db) {
            const int p1a = roff[da + 1], p1b = roff[db + 1];
            int pa = roff[da], pb = roff[db];
            const int na = (p1a - pa) >> 2, nb = (p1b - pb) >> 2;
            const int iters = na > nb ? na : nb;
            unsigned qa = *(const unsigned*)(csr + pa);
            unsigned qb = *(const unsigned*)(csr + pb);
            float a0=0.f,a1=0.f,a2=0.f,a3=0.f, c0=0.f,c1=0.f,c2=0.f,c3=0.f;
            for (int i = 0; i < iters; ++i) {
                pa += 4; pb += 4;
                const unsigned qa_n = (pa < p1a) ? *(const unsigned*)(csr + pa) : QPAD;
                const unsigned qb_n = (pb < p1b) ? *(const unsigned*)(csr + pb) : QPAD;
                float4 v;
                v = *(const float4*)(bufX + (qa & 255u) * 36 + f4);         a0+=v.x; a1+=v.y; a2+=v.z; a3+=v.w;
                v = *(const float4*)(bufX + ((qa >> 8) & 255u) * 36 + f4);  a0+=v.x; a1+=v.y; a2+=v.z; a3+=v.w;
                v = *(const float4*)(bufX + ((qa >> 16) & 255u) * 36 + f4); a0+=v.x; a1+=v.y; a2+=v.z; a3+=v.w;
                v = *(const float4*)(bufX + (qa >> 24) * 36 + f4);          a0+=v.x; a1+=v.y; a2+=v.z; a3+=v.w;
                v = *(const float4*)(bufX + (qb & 255u) * 36 + f4);         c0+=v.x; c1+=v.y; c2+=v.z; c3+=v.w;
                v = *(const float4*)(bufX + ((qb >> 8) & 255u) * 36 + f4);  c0+=v.x; c1+=v.y; c2+=v.z; c3+=v.w;
                v = *(const float4*)(bufX + ((qb >> 16) & 255u) * 36 + f4); c0+=v.x; c1+=v.y; c2+=v.z; c3+=v.w;
                v = *(const float4*)(bufX + (qb >> 24) * 36 + f4);          c0+=v.x; c1+=v.y; c2+=v.z; c3+=v.w;
                qa = qa_n; qb = qb_n;
            }
            finish(da, a0, a1, a2, a3);
            finish(db, c0, c1, c2, c3);
        };

        auto one_row = [&](int d) {
            const int p1 = roff[d + 1];
            int p = roff[d];
            const int iters = (p1 - p) >> 2;
            unsigned q = *(const unsigned*)(csr + p);
            float a0=0.f,a1=0.f,a2=0.f,a3=0.f;
            for (int i = 0; i < iters; ++i) {
                p += 4;
                const unsigned q_n = (p < p1) ? *(const unsigned*)(csr + p) : QPAD;
                float4 v;
                v = *(const float4*)(bufX + (q & 255u) * 36 + f4);         a0+=v.x; a1+=v.y; a2+=v.z; a3+=v.w;
                v = *(const float4*)(bufX + ((q >> 8) & 255u) * 36 + f4);  a0+=v.x; a1+=v.y; a2+=v.z; a3+=v.w;
                v = *(const float4*)(bufX + ((q >> 16) & 255u) * 36 + f4); a0+=v.x; a1+=v.y; a2+=v.z; a3+=v.w;
                v = *(const float4*)(bufX + (q >> 24) * 36 + f4);          a0+=v.x; a1+=v.y; a2+=v.z; a3+=v.w;
                q = q_n;
            }
            finish(d, a0, a1, a2, a3);
        };

        // Pass 1: group g takes sorted pair (perm[2g], perm[2g+1])  [ranks 0..127].
        // Pass 2 (reverse-rank): heaviest pass1 groups get lightest pass2 items.
        // Wave 0 (dsl<8) takes the 8 tiny pairs; groups 8..63 singles perm[191-dsl].
        // Coverage: pairs {184..191}x{192..199} + singles 128..183 = ranks 128..199.
        pair_rows(perm[2 * dsl], perm[2 * dsl + 1]);
        if (dsl < 8) pair_rows(perm[184 + 7 - dsl], perm[192 + 7 - dsl]);
        else         one_row(perm[191 - dsl]);
    };

    auto gemm_mid = [&](const float* __restrict__ src) {
        // bufX = (src[200x32] @ W[32x32]) scaled by dinv[row]; W staged paired in
        // wreg: [f2][k4][c][4] stride 68 (== 4 mod 32, 2-way banks). Col-pair x
        // 6-row mapping: each src b128 feeds 8 FMAs (halves activation reads).
        const int f2 = t & 15;    // column pair: cols 2*f2, 2*f2+1
        const int sl = t >> 4;    // row slot 0..31
        const float* wp = wreg + f2 * 68;
        {
            float a0A=0.f,a1A=0.f,a2A=0.f,a3A=0.f,a4A=0.f,a5A=0.f;
            float a0B=0.f,a1B=0.f,a2B=0.f,a3B=0.f,a4B=0.f,a5B=0.f;
            #pragma unroll 2
            for (int k4 = 0; k4 < 8; ++k4) {
                const float4 wA = *(const float4*)(wp + k4 * 8);
                const float4 wB = *(const float4*)(wp + k4 * 8 + 4);
                float4 v;
                v = *(const float4*)(src + (sl       ) * 36 + 4 * k4);
                a0A += v.x*wA.x + v.y*wA.y + v.z*wA.z + v.w*wA.w;
                a0B += v.x*wB.x + v.y*wB.y + v.z*wB.z + v.w*wB.w;
                v = *(const float4*)(src + (sl + 32  ) * 36 + 4 * k4);
                a1A += v.x*wA.x + v.y*wA.y + v.z*wA.z + v.w*wA.w;
                a1B += v.x*wB.x + v.y*wB.y + v.z*wB.z + v.w*wB.w;
                v = *(const float4*)(src + (sl + 64  ) * 36 + 4 * k4);
                a2A += v.x*wA.x + v.y*wA.y + v.z*wA.z + v.w*wA.w;
                a2B += v.x*wB.x + v.y*wB.y + v.z*wB.z + v.w*wB.w;
                v = *(const float4*)(src + (sl + 96  ) * 36 + 4 * k4);
                a3A += v.x*wA.x + v.y*wA.y + v.z*wA.z + v.w*wA.w;
                a3B += v.x*wB.x + v.y*wB.y + v.z*wB.z + v.w*wB.w;
                v = *(const float4*)(src + (sl + 128 ) * 36 + 4 * k4);
                a4A += v.x*wA.x + v.y*wA.y + v.z*wA.z + v.w*wA.w;
                a4B += v.x*wB.x + v.y*wB.y + v.z*wB.z + v.w*wB.w;
                v = *(const float4*)(src + (sl + 160 ) * 36 + 4 * k4);
                a5A += v.x*wA.x + v.y*wA.y + v.z*wA.z + v.w*wA.w;
                a5B += v.x*wB.x + v.y*wB.y + v.z*wB.z + v.w*wB.w;
            }
            const int c0 = 2 * f2;
            *(float2*)(bufX + (sl       ) * 36 + c0) = make_float2(dinv[sl      ] * a0A, dinv[sl      ] * a0B);
            *(float2*)(bufX + (sl + 32  ) * 36 + c0) = make_float2(dinv[sl + 32 ] * a1A, dinv[sl + 32 ] * a1B);
            *(float2*)(bufX + (sl + 64  ) * 36 + c0) = make_float2(dinv[sl + 64 ] * a2A, dinv[sl + 64 ] * a2B);
            *(float2*)(bufX + (sl + 96  ) * 36 + c0) = make_float2(dinv[sl + 96 ] * a3A, dinv[sl + 96 ] * a3B);
            *(float2*)(bufX + (sl + 128 ) * 36 + c0) = make_float2(dinv[sl + 128] * a4A, dinv[sl + 128] * a4B);
            *(float2*)(bufX + (sl + 160 ) * 36 + c0) = make_float2(dinv[sl + 160] * a5A, dinv[sl + 160] * a5B);
        }
        if (sl < 8) {   // rows 192..199
            const int r = 192 + sl;
            float aA = 0.f, aB = 0.f;
            #pragma unroll 2
            for (int k4 = 0; k4 < 8; ++k4) {
                const float4 wA = *(const float4*)(wp + k4 * 8);
                const float4 wB = *(const float4*)(wp + k4 * 8 + 4);
                const float4 v = *(const float4*)(src + r * 36 + 4 * k4);
                aA += v.x*wA.x + v.y*wA.y + v.z*wA.z + v.w*wA.w;
                aB += v.x*wB.x + v.y*wB.y + v.z*wB.z + v.w*wB.w;
            }
            *(float2*)(bufX + r * 36 + 2 * f2) = make_float2(dinv[r] * aA, dinv[r] * aB);
        }
    };

    // paired-W staging: wreg[f2*68 + k4*8 + c*4 + j] = W[(4k4+j)*32 + 2f2+c]
    auto stage_w_paired = [&](const float* __restrict__ W) {
        for (int idx = t; idx < 1024; idx += TPB) {
            const int k = idx >> 5, f = idx & 31;
            wreg[(f >> 1) * 68 + (k >> 2) * 8 + ((f & 1) << 2) + (k & 3)] = W[idx];
        }
    };

    // ---------------- Layer 1 agg (+ stage W2/b2 in-phase, bias double-buffer) --------
    agg_layer(0, 0);    // h1 -> arch[:,0:32)
    stage_w_paired(W2);
    if (t < 32) bias[32 + t] = b2[t];
    __syncthreads();

    // ---------------- Layer 2 ----------------
    gemm_mid(hcur);
    __syncthreads();
    agg_layer(32, 32);  // h2 -> arch[:,32:64)
    stage_w_paired(W3);
    if (t < 32) bias[t] = b3[t];
    __syncthreads();

    // ---------------- Layer 3 ----------------
    gemm_mid(hcur);
    __syncthreads();
    agg_layer(-1, 0);   // h3 stays in hcur (f32), not archived
    __syncthreads();

    // conv weight staging targets (bufX dead after agg3 barrier)
    float* topv = bufX;           // [30][100] = 3000 floats
    float* cw   = bufX + 3008;    // cW1: [0,1552)  cW2 stride-81: [1552,5695); ends 7151 <= 7236

    // ---------------- Layer 4 (Fout=1): scl = dinv * (h3 @ W4); scl[200]=0 ----------------
    // Idle threads 256..511 stage cW1; threads 208..255 stage conv biases.
    float* scl = (float*)(smem + OFF_CNT);   // 400 floats available (cnt+cur dead)
    if (t < MG) {
        float a = 0.f;
        #pragma unroll 8
        for (int k = 0; k < 32; ++k) a += hcur[t * 36 + k] * W4[k];
        scl[t] = dinv[t] * a;
    }
    if (t == 200) scl[200] = 0.f;
    if (t >= 256) {
        for (int idx = t - 256; idx < 1552; idx += 256) cw[idx] = cW1[idx];
    } else if (t >= 208 && t < 224) {
        bias[t - 208] = cb1[t - 208];
    } else if (t >= 224 && t < 256) {
        bias[16 + (t - 224)] = cb2[t - 224];
    }
    __syncthreads();
    // h4k gather; idle threads stage cW2 at stride 81 (odd -> no bank aliasing in conv2)
    if (t < MG) {
        const int p0 = roff[t], p1 = roff[t + 1];
        float s = 0.f;
        for (int p = p0; p < p1; p += 4) {
            const unsigned q = *(const unsigned*)(csr + p);
            s += scl[q & 255u] + scl[(q >> 8) & 255u]
               + scl[(q >> 16) & 255u] + scl[q >> 24];
        }
        h4k[t] = fast_tanh(dinv[t] * s + b4[0]);
    }
    if (t >= 256) {
        for (int idx = t - 256; idx < 2560; idx += 256) {
            const int o = idx / 80, r = idx - o * 80;
            cw[1552 + o * 81 + r] = cW2[idx];
        }
    }
    __syncthreads();

    // ---------------- SortPool: fused exact stable rank + ord scatter ----------------
    // (desc value, asc index). Each of 200 threads ranks itself over all 200
    // (same-address LDS reads broadcast -> free); scatter ord directly.
    if (t < MG) {
        const float vi = h4k[t];
        int r = 0;
        for (int j = 0; j < MG; ++j) {
            const float vj = h4k[j];
            r += (vj > vi || (vj == vi && j < t)) ? 1 : 0;
        }
        if (r < 30) ord[r] = t;
    }
    __syncthreads();

    // ---------------- Gather top-30 features ----------
    for (int idx = t; idx < 2910; idx += TPB) {   // 30*97 grid-stride
        const int kk = idx / 97;
        const int ff = idx - kk * 97;
        const int nd = ord[kk];
        float v;
        if      (ff < 64) v = __half2float(arch[(size_t)(gbase + nd) * 64 + ff]);
        else if (ff < 96) v = hcur[nd * 36 + (ff - 64)];   // h3, f32
        else              v = h4k[nd];
        topv[kk * 100 + ff] = v;
    }
    __syncthreads();

    // conv scratch in hcur (dead after gather barrier)
    float* c1p2 = hcur;           // [16][30]
    float* c1pl = hcur + 480;     // [16][16]
    float* flat = hcur + 736;     // [352]
    float* hlin = hcur + 1088;    // [128]

    // ---------------- Conv1 (97->16 per slot) + ReLU ----------------
    if (t < 480) {
        const int o  = t & 15;
        const int tt = t >> 4;
        float a = bias[o];
        const float* wrow = cw + o * 97;
        const float* trow = topv + tt * 100;
        #pragma unroll 4
        for (int f = 0; f < 97; ++f) a += wrow[f] * trow[f];
        c1p2[o * 30 + tt] = fmaxf(a, 0.f);
    }
    __syncthreads();

    // ---------------- MaxPool1d(2,2): 30 -> 15 ----------------
    if (t < 240) {
        const int o  = t & 15;
        const int tp = t >> 4;
        c1pl[o * 16 + tp] = fmaxf(c1p2[o * 30 + 2 * tp], c1p2[o * 30 + 2 * tp + 1]);
    }
    __syncthreads();

    // ---------------- Conv2 (16->32, k=5) + ReLU -> flat; init hlin ----------------
    if (t < 352) {
        const int o  = t & 31;
        const int tt = t >> 5;
        float a = bias[16 + o];
        const float* w2r = cw + 1552 + o * 81;
        #pragma unroll
        for (int i2 = 0; i2 < 16; ++i2) {
            #pragma unroll
            for (int kk = 0; kk < 5; ++kk)
                a += w2r[i2 * 5 + kk] * c1pl[i2 * 16 + tt + kk];
        }
        flat[o * 11 + tt] = fmaxf(a, 0.f);
    } else if (t >= 352 && t < 480) {
        hlin[t - 352] = lb1[t - 352];
    }
    __syncthreads();

    // ---------------- Linear 352->128 (split-K over 4 groups of 88) ----------------
    {
        const int f  = t & 127;
        const int kc = t >> 7;   // 0..3
        float a = 0.f;
        const int k0 = kc * 88;
        #pragma unroll 4
        for (int kk = k0; kk < k0 + 88; ++kk) a += flat[kk] * lW1[kk * 128 + f];
        atomicAdd(&hlin[f], a);
    }
    __syncthreads();

    // ---------------- ReLU -> Linear 128->1 -> sigmoid ----------------
    if (t < 128) {
        float p = fmaxf(hlin[t], 0.f) * lW2[t];
        #pragma unroll
        for (int off = 32; off > 0; off >>= 1) p += __shfl_down(p, off);
        if ((t & 63) == 0) red[t >> 6] = p;
    }
    __syncthreads();
    if (t == 0) {
        const float z = red[0] + red[1] + lb2[0];
        out[g] = 1.f / (1.f + expf(-z));
    }
}

extern "C" void kernel_launch(void* const* d_in, const int* in_sizes, int n_in,
                              void* d_out, int out_size, void* d_ws, size_t ws_size,
                              hipStream_t stream) {
    (void)in_sizes; (void)n_in; (void)out_size; (void)ws_size;
    const float* x   = (const float*)d_in[0];
    const int*   ei  = (const int*)d_in[1];
    const float* W1  = (const float*)d_in[3];  const float* b1  = (const float*)d_in[4];
    const float* W2  = (const float*)d_in[5];  const float* b2  = (const float*)d_in[6];
    const float* W3  = (const float*)d_in[7];  const float* b3  = (const float*)d_in[8];
    const float* W4  = (const float*)d_in[9];  const float* b4  = (const float*)d_in[10];
    const float* cW1 = (const float*)d_in[11]; const float* cb1 = (const float*)d_in[12];
    const float* cW2 = (const float*)d_in[13]; const float* cb2 = (const float*)d_in[14];
    const float* lW1 = (const float*)d_in[15]; const float* lb1 = (const float*)d_in[16];
    const float* lW2 = (const float*)d_in[17]; const float* lb2 = (const float*)d_in[18];
    float* out = (float*)d_out;
    __half* arch = (__half*)d_ws;   // needs 512*200*64*2 = 13.1 MB

    hipFuncSetAttribute((const void*)dgcnn_kernel,
                        hipFuncAttributeMaxDynamicSharedMemorySize, SMEM_BYTES);

    dgcnn_kernel<<<GRID, TPB, SMEM_BYTES, stream>>>(
        x, ei, W1, b1, W2, b2, W3, b3, W4, b4,
        cW1, cb1, cW2, cb2, lW1, lb1, lW2, lb2, arch, out);
}